// Round 9
// baseline (105.135 us; speedup 1.0000x reference)
//
#include <hip/hip_runtime.h>

// Sizes (static, from reference)
#define NSUB 65536
#define NV0 10242
#define NV1 40962
#define NV2 163842
#define EPSV 1e-5f
#define SPLITK 16

__device__ inline float wave_red(float v) {
#pragma unroll
    for (int off = 32; off > 0; off >>= 1) v += __shfl_down(v, off, 64);
    return v;
}

// Block-reduce vals[16] (layout: [c]=sum, [8+c]=sumsq for c<NCH) and
// atomicAdd into slot (16 floats). All 256 threads must reach this.
// No fences: plain device-scope atomics; cross-kernel visibility via stream order.
template <int NCH>
__device__ inline void emit_stats(const float* vals, float* __restrict__ slot,
                                  float* stl /*shared [64]*/) {
    int t = threadIdx.x;
    float r[2 * NCH];
#pragma unroll
    for (int c = 0; c < NCH; ++c) {
        r[c] = wave_red(vals[c]);
        r[NCH + c] = wave_red(vals[8 + c]);
    }
    if ((t & 63) == 0) {
#pragma unroll
        for (int i = 0; i < 2 * NCH; ++i) stl[(t >> 6) * 16 + i] = r[i];
    }
    __syncthreads();
    if (t < 2 * NCH) {
        float v = stl[t] + stl[16 + t] + stl[32 + t] + stl[48 + t];
        int idx = (t < NCH) ? t : 8 + (t - NCH);
        atomicAdd(slot + idx, v);
    }
}

// Consumer prologue: derive BN scale/shift from raw sums. sS[c]=scale, sS[8+c]=shift.
template <int NCH>
__device__ inline void bn_from_sums(const float* __restrict__ slot, float n,
                                    const float* __restrict__ g,
                                    const float* __restrict__ b, float* sS) {
    int t = threadIdx.x;
    if (t < NCH) {
        float m = slot[t] / n;
        float var = slot[8 + t] / n - m * m;
        float scale = rsqrtf(var + EPSV) * g[t];
        sS[t] = scale;
        sS[8 + t] = b[t] - m * scale;
    }
}

// ---------------------------------------------------------------------------
// gemv1 split-K partials: y1p[s*256+o] = sub[slice s] . W_sub[o, slice s]
__global__ __launch_bounds__(256) void k_gemv1(const float* __restrict__ sub,
                                               const float* __restrict__ Ws,
                                               float* __restrict__ y1p) {
    int task = blockIdx.x, o = task >> 4, s = task & (SPLITK - 1);
    const float* row = Ws + (size_t)o * NSUB + s * (NSUB / SPLITK);
    const float* sb = sub + s * (NSUB / SPLITK);
    int t = threadIdx.x;
    int i0 = t * 4, i1 = (256 + t) * 4, i2 = (512 + t) * 4, i3 = (768 + t) * 4;
    float4 xa = *(const float4*)(sb + i0), wa = *(const float4*)(row + i0);
    float4 xb = *(const float4*)(sb + i1), wb = *(const float4*)(row + i1);
    float4 xc = *(const float4*)(sb + i2), wc = *(const float4*)(row + i2);
    float4 xd = *(const float4*)(sb + i3), wd = *(const float4*)(row + i3);
    float a0 = xa.x * wa.x + xa.y * wa.y + xa.z * wa.z + xa.w * wa.w;
    float a1 = xb.x * wb.x + xb.y * wb.y + xb.z * wb.z + xb.w * wb.w;
    float a2 = xc.x * wc.x + xc.y * wc.y + xc.z * wc.z + xc.w * wc.w;
    float a3 = xd.x * wd.x + xd.y * wd.y + xd.z * wd.z + xd.w * wd.w;
    float acc = wave_red((a0 + a1) + (a2 + a3));
    __shared__ float red[4];
    if ((t & 63) == 0) red[t >> 6] = acc;
    __syncthreads();
    if (t == 0) y1p[s * 256 + o] = red[0] + red[1] + red[2] + red[3];
}

// ---------------------------------------------------------------------------
// bridge: y1[o] = b_sub[o] + sum_s y1p[s][o]; zero the 5x16 stat slots
__global__ __launch_bounds__(256) void k_bridge(const float* __restrict__ bs,
                                                const float* __restrict__ y1p,
                                                float* __restrict__ y1,
                                                float* __restrict__ slots) {
    int t = threadIdx.x;
    float acc = bs[t];
#pragma unroll
    for (int s = 0; s < SPLITK; ++s) acc += y1p[s * 256 + t];
    y1[t] = acc;
    if (t < 80) slots[t] = 0.f;
}

// ---------------------------------------------------------------------------
// x0[o] = y1 . W_fc[o,:] + b_fc[o]; wave per output
__global__ __launch_bounds__(256) void k_gemv2(const float* __restrict__ y1,
                                               const float* __restrict__ Wf,
                                               const float* __restrict__ bfc,
                                               float* __restrict__ x0) {
    int o = blockIdx.x * 4 + (threadIdx.x >> 6);
    int ln = threadIdx.x & 63;
    if (o >= 3 * NV0) return;
    const float* row = Wf + (size_t)o * 256;
    float4 w4 = *(const float4*)(row + ln * 4);
    float4 yv = *(const float4*)(y1 + ln * 4);
    float acc = wave_red(w4.x * yv.x + w4.y * yv.y + w4.z * yv.z + w4.w * yv.w);
    if (ln == 0) x0[o] = acc + bfc[o];
}

// ---------------------------------------------------------------------------
// stats of x0 [NV0,3] -> slot st0 (atomics, no fences)
__global__ __launch_bounds__(256) void k_stats3(const float* __restrict__ x,
                                                float* __restrict__ slot) {
    __shared__ float stl[64];
    int t = threadIdx.x;
    float vals[16];
#pragma unroll
    for (int i = 0; i < 16; ++i) vals[i] = 0.f;
    for (int v = blockIdx.x * 256 + t; v < NV0; v += 64 * 256) {
        float a = x[v * 3 + 0], b = x[v * 3 + 1], c = x[v * 3 + 2];
        vals[0] += a; vals[1] += b; vals[2] += c;
        vals[8] += a * a; vals[9] += b * b; vals[10] += c * c;
    }
    emit_stats<3>(vals, slot, stl);
}

// ---------------------------------------------------------------------------
// upconv + fused output stats (plain atomics)
__global__ __launch_bounds__(256) void k_upconv(const float* __restrict__ xin, int nIn, int nOut,
                                                const float* __restrict__ slotIn,
                                                float* __restrict__ slotOut,
                                                const float* __restrict__ gIn,
                                                const float* __restrict__ bIn,
                                                const float* __restrict__ W,
                                                const float* __restrict__ bias,
                                                const int* __restrict__ top,
                                                const int* __restrict__ down,
                                                float* __restrict__ xout) {
    __shared__ float sW[63], sB[21], sS[16], stl[64];
    int t = threadIdx.x;
    if (t >= 64 && t < 127) sW[t - 64] = W[t - 64];
    if (t >= 128 && t < 149) sB[t - 128] = bias[t - 128];
    bn_from_sums<3>(slotIn, (float)nIn, gIn, bIn, sS);
    __syncthreads();

    int v = blockIdx.x * 256 + t;
    bool ok = v < nOut;
    float o0 = 0.f, o1 = 0.f, o2 = 0.f;
    if (ok) {
        auto uval = [&](int idx, float* o3) {
            int src = idx / 7;
            int j = idx - src * 7;
            float a0 = xin[src * 3 + 0] * sS[0] + sS[8];  a0 = a0 > 0.f ? a0 : 0.2f * a0;
            float a1 = xin[src * 3 + 1] * sS[1] + sS[9];  a1 = a1 > 0.f ? a1 : 0.2f * a1;
            float a2 = xin[src * 3 + 2] * sS[2] + sS[10]; a2 = a2 > 0.f ? a2 : 0.2f * a2;
#pragma unroll
            for (int c = 0; c < 3; ++c) {
                int rr = j * 3 + c;
                o3[c] = sB[rr] + a0 * sW[rr * 3 + 0] + a1 * sW[rr * 3 + 1] + a2 * sW[rr * 3 + 2];
            }
        };
        if (v < nIn) {
            float o3[3];
            uval(top[v], o3);
            o0 = o3[0]; o1 = o3[1]; o2 = o3[2];
        } else {
            int i = v - nIn;
            float a[3], bb[3];
            uval(down[2 * i], a);
            uval(down[2 * i + 1], bb);
            o0 = 0.5f * (a[0] + a[1]);
            o1 = 0.5f * (a[2] + bb[0]);
            o2 = 0.5f * (bb[1] + bb[2]);
        }
        xout[(size_t)v * 3 + 0] = o0;
        xout[(size_t)v * 3 + 1] = o1;
        xout[(size_t)v * 3 + 2] = o2;
    }
    float vals[16];
#pragma unroll
    for (int i = 0; i < 16; ++i) vals[i] = 0.f;
    vals[0] = o0; vals[1] = o1; vals[2] = o2;
    vals[8] = o0 * o0; vals[9] = o1 * o1; vals[10] = o2 * o2;
    emit_stats<3>(vals, slotOut, stl);
}

// ---------------------------------------------------------------------------
// one-ring conv, 2 vertices/thread for gather MLP + optional fused stats
template <int CIN, int COUT, bool EMIT>
__global__ __launch_bounds__(256) void k_onering(const float* __restrict__ xin,
                                                 const float* __restrict__ slotIn,
                                                 float* __restrict__ slotOut,
                                                 const float* __restrict__ gIn,
                                                 const float* __restrict__ bIn,
                                                 const float* __restrict__ W,
                                                 const float* __restrict__ bias,
                                                 const int* __restrict__ neigh,
                                                 float* __restrict__ out) {
    __shared__ float sW[COUT * 7 * CIN], sB[COUT], sS[16], stl[64];
    int t = threadIdx.x;
    for (int i = t; i < COUT * 7 * CIN; i += 256) sW[i] = W[i];
    if (t >= 32 && t < 32 + COUT) sB[t - 32] = bias[t - 32];
    bn_from_sums<CIN>(slotIn, (float)NV2, gIn, bIn, sS);
    __syncthreads();

    int v0 = blockIdx.x * 512 + t;
    int v1 = v0 + 256;
    bool ok0 = v0 < NV2, ok1 = v1 < NV2;

    // prefetch all neighbor indices (up to 14 independent loads)
    int nb0[7], nb1[7];
    const int* np0 = neigh + (size_t)v0 * 7;
    const int* np1 = neigh + (size_t)v1 * 7;
#pragma unroll
    for (int j = 0; j < 7; ++j) nb0[j] = ok0 ? np0[j] : 0;
#pragma unroll
    for (int j = 0; j < 7; ++j) nb1[j] = ok1 ? np1[j] : 0;

    float acc0[COUT], acc1[COUT];
#pragma unroll
    for (int c = 0; c < COUT; ++c) { acc0[c] = sB[c]; acc1[c] = sB[c]; }

    auto body = [&](const int* nb, float* acc) {
#pragma unroll
        for (int j = 0; j < 7; ++j) {
            float tv[CIN];
            if (CIN == 8) {
                float4 A = *(const float4*)(xin + (size_t)nb[j] * 8);
                float4 Bv = *(const float4*)(xin + (size_t)nb[j] * 8 + 4);
                float raw[8] = {A.x, A.y, A.z, A.w, Bv.x, Bv.y, Bv.z, Bv.w};
#pragma unroll
                for (int k = 0; k < 8; ++k) {
                    float x = raw[k] * sS[k] + sS[8 + k];
                    tv[k] = x > 0.f ? x : 0.2f * x;
                }
            } else {
#pragma unroll
                for (int k = 0; k < CIN; ++k) {
                    float x = xin[(size_t)nb[j] * CIN + k] * sS[k] + sS[8 + k];
                    tv[k] = x > 0.f ? x : 0.2f * x;
                }
            }
#pragma unroll
            for (int c = 0; c < COUT; ++c) {
                float a = acc[c];
#pragma unroll
                for (int k = 0; k < CIN; ++k) a += tv[k] * sW[c * 7 * CIN + j * CIN + k];
                acc[c] = a;
            }
        }
    };
    if (ok0) body(nb0, acc0);
    if (ok1) body(nb1, acc1);

    if (ok0) {
        if (COUT == 8) {
            float4 A = {acc0[0], acc0[1], acc0[2], acc0[3]};
            float4 Bv = {acc0[4], acc0[5], acc0[6], acc0[7]};
            *(float4*)(out + (size_t)v0 * 8) = A;
            *(float4*)(out + (size_t)v0 * 8 + 4) = Bv;
        } else {
#pragma unroll
            for (int c = 0; c < COUT; ++c) out[(size_t)v0 * COUT + c] = acc0[c];
        }
    }
    if (ok1) {
        if (COUT == 8) {
            float4 A = {acc1[0], acc1[1], acc1[2], acc1[3]};
            float4 Bv = {acc1[4], acc1[5], acc1[6], acc1[7]};
            *(float4*)(out + (size_t)v1 * 8) = A;
            *(float4*)(out + (size_t)v1 * 8 + 4) = Bv;
        } else {
#pragma unroll
            for (int c = 0; c < COUT; ++c) out[(size_t)v1 * COUT + c] = acc1[c];
        }
    }

    if (EMIT) {
        float vals[16];
#pragma unroll
        for (int i = 0; i < 16; ++i) vals[i] = 0.f;
#pragma unroll
        for (int c = 0; c < COUT; ++c) {
            float a = ok0 ? acc0[c] : 0.f;
            float b = ok1 ? acc1[c] : 0.f;
            vals[c] = a + b;
            vals[8 + c] = a * a + b * b;
        }
        emit_stats<COUT>(vals, slotOut, stl);
    }
}

// ---------------------------------------------------------------------------
extern "C" void kernel_launch(void* const* d_in, const int* in_sizes, int n_in,
                              void* d_out, int out_size, void* d_ws, size_t ws_size,
                              hipStream_t stream) {
    const float* sub_id = (const float*)d_in[0];
    const float* W_sub  = (const float*)d_in[1];
    const float* b_sub  = (const float*)d_in[2];
    const float* W_fc   = (const float*)d_in[3];
    const float* b_fc   = (const float*)d_in[4];
    const float* bn_u0g = (const float*)d_in[5];
    const float* bn_u0b = (const float*)d_in[6];
    const float* up0_W  = (const float*)d_in[7];
    const float* up0_b  = (const float*)d_in[8];
    const float* bn_u1g = (const float*)d_in[9];
    const float* bn_u1b = (const float*)d_in[10];
    const float* up1_W  = (const float*)d_in[11];
    const float* up1_b  = (const float*)d_in[12];
    const float* bn0g   = (const float*)d_in[13];
    const float* bn0b   = (const float*)d_in[14];
    const float* c0_W   = (const float*)d_in[15];
    const float* c0_b   = (const float*)d_in[16];
    const float* bn1g   = (const float*)d_in[17];
    const float* bn1b   = (const float*)d_in[18];
    const float* c1_W   = (const float*)d_in[19];
    const float* c1_b   = (const float*)d_in[20];
    const float* bn2g   = (const float*)d_in[21];
    const float* bn2b   = (const float*)d_in[22];
    const float* c2_W   = (const float*)d_in[23];
    const float* c2_b   = (const float*)d_in[24];
    const int* neigh  = (const int*)d_in[25];
    const int* top0   = (const int*)d_in[26];
    const int* down0  = (const int*)d_in[27];
    const int* top1   = (const int*)d_in[28];
    const int* down1  = (const int*)d_in[29];

    float* ws = (float*)d_ws;
    float* y1p   = ws + 0;          // 4096
    float* y1    = ws + 4096;       // 256
    float* x0    = ws + 4352;       // 30726
    float* xA    = ws + 35080;      // 122886
    float* xB    = ws + 157968;     // 491526
    float* h0    = ws + 649496;     // 1310736 (16B aligned)
    float* h1    = ws + 1960232;    // 1310736 (16B aligned)
    float* slots = ws + 3270968;    // 5 * 16

    float* st0 = slots + 0;
    float* st1 = slots + 16;
    float* st2 = slots + 32;
    float* st3 = slots + 48;
    float* st4 = slots + 64;

    const unsigned NB1  = (NV1 + 255) / 256;   // 161
    const unsigned NB2  = (NV2 + 255) / 256;   // 641
    const unsigned NB2h = (NV2 + 511) / 512;   // 321

    k_gemv1<<<256 * SPLITK, 256, 0, stream>>>(sub_id, W_sub, y1p);
    k_bridge<<<1, 256, 0, stream>>>(b_sub, y1p, y1, slots);
    k_gemv2<<<(3 * NV0 + 3) / 4, 256, 0, stream>>>(y1, W_fc, b_fc, x0);
    k_stats3<<<64, 256, 0, stream>>>(x0, st0);

    k_upconv<<<NB1, 256, 0, stream>>>(x0, NV0, NV1, st0, st1,
                                      bn_u0g, bn_u0b, up0_W, up0_b, top0, down0, xA);
    k_upconv<<<NB2, 256, 0, stream>>>(xA, NV1, NV2, st1, st2,
                                      bn_u1g, bn_u1b, up1_W, up1_b, top1, down1, xB);

    k_onering<3, 8, true><<<NB2h, 256, 0, stream>>>(
        xB, st2, st3, bn0g, bn0b, c0_W, c0_b, neigh, h0);
    k_onering<8, 8, true><<<NB2h, 256, 0, stream>>>(
        h0, st3, st4, bn1g, bn1b, c1_W, c1_b, neigh, h1);
    k_onering<8, 2, false><<<NB2h, 256, 0, stream>>>(
        h1, st4, nullptr, bn2g, bn2b, c2_W, c2_b, neigh, (float*)d_out);
}